// Round 11
// baseline (2157.022 us; speedup 1.0000x reference)
//
#include <hip/hip_runtime.h>

#define NP 200000
#define NU 100000
#define NBR 5000
#define NCAT 2000
#define NSH 1000
#define NN (NP + NU + NBR + NCAT + NSH) /* 308000 */
#define OFF_U NP
#define OFF_B (NP + NU)
#define OFF_C (NP + NU + NBR)
#define OFF_S (NP + NU + NBR + NCAT)

#define NBINS 67 /* class-aware node bins: 25 P(8192) + 13 U(8192) + 5 B(1024) + 8 C(256) + 16 S(64) */

typedef unsigned short u16;
typedef unsigned int u32;
typedef __attribute__((ext_vector_type(8))) short short8;
typedef __attribute__((ext_vector_type(4))) float f32x4;

__device__ __forceinline__ u16 f2bf(float f) {
  union { float f; unsigned u; } v;
  v.f = f;
  unsigned r = (v.u + 0x7fffu + ((v.u >> 16) & 1u)) >> 16;  // RNE
  return (u16)r;
}
__device__ __forceinline__ float uasf(u32 u) {
  union { u32 u; float f; } v;
  v.u = u;
  return v.f;
}
// pack 2 fp32 -> 2 bf16 (RNE) in one instr
__device__ __forceinline__ u32 cvtpk(float lo, float hi) {
  u32 r;
  asm("v_cvt_pk_bf16_f32 %0, %1, %2" : "=v"(r) : "v"(lo), "v"(hi));
  return r;
}

// node -> bin (class-aware ranges; each bin spans <= 8192 nodes)
__device__ __forceinline__ int bin_of(int a) {
  if (a < OFF_U) return a >> 13;
  if (a < OFF_B) return 25 + ((a - OFF_U) >> 13);
  if (a < OFF_C) return 38 + ((a - OFF_B) >> 10);
  if (a < OFF_S) return 43 + ((a - OFF_C) >> 8);
  return 51 + ((a - OFF_S) >> 6);
}
__device__ __forceinline__ void bin_range(int bin, int& n0, int& n1) {
  if (bin < 25) {
    n0 = bin << 13; n1 = min(n0 + 8192, OFF_U);
  } else if (bin < 38) {
    n0 = OFF_U + ((bin - 25) << 13); n1 = min(n0 + 8192, OFF_B);
  } else if (bin < 43) {
    n0 = OFF_B + ((bin - 38) << 10); n1 = min(n0 + 1024, OFF_C);
  } else if (bin < 51) {
    n0 = OFF_C + ((bin - 43) << 8); n1 = min(n0 + 256, OFF_S);
  } else {
    n0 = OFF_S + ((bin - 51) << 6); n1 = min(n0 + 64, NN);
  }
}

// ---------------------------------------------------------------------------
// MFMA projection: xb[r][c] = bf16(relu(px[r][:] @ W[:][c] + b[c])), r<NP.
// ---------------------------------------------------------------------------
__global__ __launch_bounds__(256) void proj_mfma_kernel(
    const float* __restrict__ px, const float* __restrict__ W,
    const float* __restrict__ bias, u16* __restrict__ xb) {
  __shared__ u16 lA[2][128 * 32];  // 8 KB per buffer, bf16, swizzled
  const int t = threadIdx.x;
  const int l = t & 63;
  const int wid = t >> 6;
  const int row0 = blockIdx.x * 128;

  const int n0 = wid * 16 + (l & 15);
  const int kb = (l >> 4) * 8;
  short8 bf[12];
#pragma unroll
  for (int kt = 0; kt < 12; ++kt) {
    union { u32 p[4]; short8 s; } uu;
#pragma unroll
    for (int j = 0; j < 4; ++j) {
      const float lo = W[(size_t)(kt * 32 + kb + 2 * j) * 64 + n0];
      const float hi = W[(size_t)(kt * 32 + kb + 2 * j + 1) * 64 + n0];
      uu.p[j] = cvtpk(lo, hi);
    }
    bf[kt] = uu.s;
  }
  const float bv = bias[n0];

  f32x4 acc[8];
#pragma unroll
  for (int rt = 0; rt < 8; ++rt) {
    f32x4 z = {0.f, 0.f, 0.f, 0.f};
    acc[rt] = z;
  }

  const int fr_base = (((l & 15) * 64 + (l >> 4) * 16)) ^ ((l & 7) << 4);

  float4 sreg[4];
#pragma unroll
  for (int i = 0; i < 4; ++i) {
    const int qi = t + 256 * i;
    const int r = qi >> 3, q = qi & 7;
    const int grow = row0 + r;
    sreg[i] = (grow < NP) ? *reinterpret_cast<const float4*>(px + (size_t)grow * 384 + q * 4)
                          : make_float4(0.f, 0.f, 0.f, 0.f);
  }
#pragma unroll
  for (int i = 0; i < 4; ++i) {
    const int qi = t + 256 * i;
    const int r = qi >> 3, q = qi & 7;
    const int a16 = (((r * 64 + q * 8)) ^ ((r & 7) << 4)) >> 1;
    const u32 p0 = cvtpk(sreg[i].x, sreg[i].y);
    const u32 p1 = cvtpk(sreg[i].z, sreg[i].w);
    *reinterpret_cast<uint2*>(&lA[0][a16]) = make_uint2(p0, p1);
  }

#pragma unroll
  for (int kt = 0; kt < 12; ++kt) {
    const int cur = kt & 1;
    if (kt + 1 < 12) {
#pragma unroll
      for (int i = 0; i < 4; ++i) {
        const int qi = t + 256 * i;
        const int r = qi >> 3, q = qi & 7;
        const int grow = row0 + r;
        sreg[i] = (grow < NP)
                      ? *reinterpret_cast<const float4*>(px + (size_t)grow * 384 +
                                                         (kt + 1) * 32 + q * 4)
                      : make_float4(0.f, 0.f, 0.f, 0.f);
      }
    }
    __syncthreads();
#pragma unroll
    for (int rt = 0; rt < 8; ++rt) {
      const short8 af =
          *reinterpret_cast<const short8*>(&lA[cur][(fr_base + rt * 1024) >> 1]);
      acc[rt] = __builtin_amdgcn_mfma_f32_16x16x32_bf16(af, bf[kt], acc[rt], 0, 0, 0);
    }
    if (kt + 1 < 12) {
#pragma unroll
      for (int i = 0; i < 4; ++i) {
        const int qi = t + 256 * i;
        const int r = qi >> 3, q = qi & 7;
        const int a16 = (((r * 64 + q * 8)) ^ ((r & 7) << 4)) >> 1;
        const u32 p0 = cvtpk(sreg[i].x, sreg[i].y);
        const u32 p1 = cvtpk(sreg[i].z, sreg[i].w);
        *reinterpret_cast<uint2*>(&lA[cur ^ 1][a16]) = make_uint2(p0, p1);
      }
    }
  }

#pragma unroll
  for (int rt = 0; rt < 8; ++rt) {
#pragma unroll
    for (int r = 0; r < 4; ++r) {
      const int grow = row0 + rt * 16 + (l >> 4) * 4 + r;
      if (grow < NP)
        xb[(size_t)grow * 64 + n0] = f2bf(fmaxf(acc[rt][r] + bv, 0.f));
    }
  }
}

// ---------------------------------------------------------------------------
// Fused fp32->bf16 conversion of all 4 embedding tables into xb.
// ---------------------------------------------------------------------------
__global__ void cvt_emb_kernel(const float* __restrict__ ue, const float* __restrict__ be,
                               const float* __restrict__ ce, const float* __restrict__ se,
                               u16* __restrict__ xb) {
  const int i = blockIdx.x * 256 + threadIdx.x;
  const int totalQ = (NU + NBR + NCAT + NSH) * 16;
  if (i >= totalQ) return;
  const int row = i >> 4, q = i & 15;
  const float* src;
  int lrow;
  if (row < NU) {
    src = ue; lrow = row;
  } else if (row < NU + NBR) {
    src = be; lrow = row - NU;
  } else if (row < NU + NBR + NCAT) {
    src = ce; lrow = row - NU - NBR;
  } else {
    src = se; lrow = row - NU - NBR - NCAT;
  }
  const float4 v = reinterpret_cast<const float4*>(src)[(size_t)lrow * 16 + q];
  ushort4 o;
  o.x = f2bf(v.x);
  o.y = f2bf(v.y);
  o.z = f2bf(v.z);
  o.w = f2bf(v.w);
  reinterpret_cast<ushort4*>(xb + (size_t)(OFF_U + row) * 64)[q] = o;
}

// ---------------------------------------------------------------------------
// Directed-entry decode. i in [0, 2*nE).
// ---------------------------------------------------------------------------
__device__ __forceinline__ void decode_edge(
    int i, const int* pbs, const int* pbd, const int* pcs, const int* pcd,
    const int* pss, const int* psd, const int* ups, const int* upd,
    int nPB, int nPC, int nPS, int& a, int& b) {
  const int d = i & 1;
  int eu = i >> 1;
  int a0, b0;
  if (eu < nPB) {
    a0 = pbs[eu]; b0 = pbd[eu] + OFF_B;
  } else {
    eu -= nPB;
    if (eu < nPC) {
      a0 = pcs[eu]; b0 = pcd[eu] + OFF_C;
    } else {
      eu -= nPC;
      if (eu < nPS) {
        a0 = pss[eu]; b0 = psd[eu] + OFF_S;
      } else {
        eu -= nPS;
        a0 = ups[eu] + OFF_U; b0 = upd[eu];
      }
    }
  }
  a = d ? b0 : a0;
  b = d ? a0 : b0;
}

#define EDGE_ARGS const int* __restrict__ pbs, const int* __restrict__ pbd, \
                  const int* __restrict__ pcs, const int* __restrict__ pcd, \
                  const int* __restrict__ pss, const int* __restrict__ psd, \
                  const int* __restrict__ ups, const int* __restrict__ upd, \
                  int nPB, int nPC, int nPS, int nD
#define EDGE_PASS pbs, pbd, pcs, pcd, pss, psd, ups, upd, nPB, nPC, nPS

// ---------------------------------------------------------------------------
// 1. Global histogram of directed entries per node-bin (34k global atomics).
// ---------------------------------------------------------------------------
__global__ __launch_bounds__(256) void bin_count_kernel(EDGE_ARGS,
                                                        int* __restrict__ binCnt) {
  __shared__ int lh[NBINS];
  const int t = threadIdx.x;
  if (t < NBINS) lh[t] = 0;
  __syncthreads();
  for (int i = blockIdx.x * 256 + t; i < nD; i += gridDim.x * 256) {
    int a, b;
    decode_edge(i, EDGE_PASS, a, b);
    (void)b;
    atomicAdd(&lh[bin_of(a)], 1);
  }
  __syncthreads();
  if (t < NBINS && lh[t] > 0) atomicAdd(&binCnt[t], lh[t]);
}

// 2. Tiny scan: binCnt[NBINS] -> binBase[NBINS+1]; init gcur.
__global__ void bin_scan_kernel(const int* __restrict__ binCnt, int* __restrict__ binBase,
                                int* __restrict__ gcur) {
  __shared__ int base[NBINS + 1];
  if (threadIdx.x == 0) {
    int run = 0;
    for (int b = 0; b < NBINS; ++b) {
      base[b] = run;
      run += binCnt[b];
    }
    base[NBINS] = run;
  }
  __syncthreads();
  if (threadIdx.x <= NBINS) binBase[threadIdx.x] = base[threadIdx.x];
  if (threadIdx.x < NBINS) gcur[threadIdx.x * 16] = base[threadIdx.x];
}

// ---------------------------------------------------------------------------
// 3. Two-phase block binning by node-bin: LDS hist -> one gcur reserve per
//    bin per block -> re-decode (L2-hot) -> grouped coalesced record writes.
// ---------------------------------------------------------------------------
__global__ __launch_bounds__(256) void bin_scatter_kernel(EDGE_ARGS,
                                                          uint2* __restrict__ gbuf,
                                                          int* __restrict__ gcur) {
  __shared__ int lh[NBINS];
  __shared__ int gb[NBINS];
  __shared__ int ofs[NBINS];
  const int t = threadIdx.x;
  const int per = (nD + gridDim.x - 1) / gridDim.x;
  const int start = blockIdx.x * per;
  const int end = (start + per < nD) ? (start + per) : nD;

  if (t < NBINS) {
    lh[t] = 0;
    ofs[t] = 0;
  }
  __syncthreads();
  for (int i = start + t; i < end; i += 256) {
    int a, b;
    decode_edge(i, EDGE_PASS, a, b);
    (void)b;
    atomicAdd(&lh[bin_of(a)], 1);
  }
  __syncthreads();
  if (t < NBINS && lh[t] > 0) gb[t] = atomicAdd(&gcur[t * 16], lh[t]);
  __syncthreads();
  for (int i = start + t; i < end; i += 256) {
    int a, b;
    decode_edge(i, EDGE_PASS, a, b);
    const int bb = bin_of(a);
    const int d = atomicAdd(&ofs[bb], 1);
    gbuf[gb[bb] + d] = make_uint2((u32)a, (u32)b);
  }
}

// ---------------------------------------------------------------------------
// 4. Per-bin-slice node counting: LDS counters, coalesced partial writes.
// ---------------------------------------------------------------------------
__global__ __launch_bounds__(256) void count_nodes_kernel(
    const uint2* __restrict__ gbuf, const int* __restrict__ binBase,
    int* __restrict__ cntp) {
  __shared__ int cnt[8192];
  const int bin = blockIdx.x >> 2, s = blockIdx.x & 3;
  int n0, n1;
  bin_range(bin, n0, n1);
  const int rb = binBase[bin], re = binBase[bin + 1];
  const int len = re - rb;
  const int s0 = rb + (len * s) / 4;
  const int s1 = rb + (len * (s + 1)) / 4;
  for (int i = threadIdx.x; i < 8192; i += 256) cnt[i] = 0;
  __syncthreads();
  for (int r = s0 + threadIdx.x; r < s1; r += 256)
    atomicAdd(&cnt[(int)gbuf[r].x - n0], 1);
  __syncthreads();
  for (int n = n0 + threadIdx.x; n < n1; n += 256)
    cntp[s * NN + n] = cnt[n - n0];
}

// 3-kernel exclusive scan over sum of 4 partials -> rowptr[NN+1]
__global__ __launch_bounds__(256) void scan1_kernel(const int* __restrict__ cntp,
                                                    int* __restrict__ blockSums, int n) {
  __shared__ int sdata[256];
  const int base = blockIdx.x * 1024;
  int s = 0;
  for (int i = threadIdx.x; i < 1024; i += 256) {
    int idx = base + i;
    if (idx < n)
      s += cntp[idx] + cntp[NN + idx] + cntp[2 * NN + idx] + cntp[3 * NN + idx];
  }
  sdata[threadIdx.x] = s;
  __syncthreads();
  for (int off = 128; off > 0; off >>= 1) {
    if (threadIdx.x < off) sdata[threadIdx.x] += sdata[threadIdx.x + off];
    __syncthreads();
  }
  if (threadIdx.x == 0) blockSums[blockIdx.x] = sdata[0];
}

__global__ __launch_bounds__(512) void scan2_kernel(int* __restrict__ blockSums, int nb) {
  __shared__ int sd[512];
  const int t = threadIdx.x;
  const int v = (t < nb) ? blockSums[t] : 0;
  sd[t] = v;
  __syncthreads();
  for (int off = 1; off < 512; off <<= 1) {
    int add = (t >= off) ? sd[t - off] : 0;
    __syncthreads();
    sd[t] += add;
    __syncthreads();
  }
  if (t < nb) blockSums[t] = sd[t] - v;  // exclusive
}

__global__ __launch_bounds__(256) void scan3_kernel(const int* __restrict__ cntp,
                                                    const int* __restrict__ blockSums,
                                                    int* __restrict__ rowptr, int n) {
  __shared__ int wsum[4];
  const int base = blockIdx.x * 1024;
  const int t = threadIdx.x, lane = t & 63, wid = t >> 6;
  const int idx0 = base + t * 4;
  int v[4];
#pragma unroll
  for (int j = 0; j < 4; ++j) {
    int idx = idx0 + j;
    v[j] = (idx < n)
               ? cntp[idx] + cntp[NN + idx] + cntp[2 * NN + idx] + cntp[3 * NN + idx]
               : 0;
  }
  const int s = v[0] + v[1] + v[2] + v[3];
  int incl = s;
  for (int off = 1; off < 64; off <<= 1) {
    int tt = __shfl_up(incl, off);
    if (lane >= off) incl += tt;
  }
  if (lane == 63) wsum[wid] = incl;
  __syncthreads();
  int wOff = 0;
#pragma unroll
  for (int w = 0; w < 4; ++w)
    if (w < wid) wOff += wsum[w];
  int run = blockSums[blockIdx.x] + wOff + (incl - s);
#pragma unroll
  for (int j = 0; j < 4; ++j) {
    int idx = idx0 + j;
    if (idx < n) {
      rowptr[idx] = run;
      run += v[j];
      if (idx == n - 1) rowptr[n] = run;
    }
  }
}

// ---------------------------------------------------------------------------
// 6. Final fill: LDS cursor, LDS-atomic position assignment, windowed scatter.
// ---------------------------------------------------------------------------
__global__ __launch_bounds__(256) void fill_scatter_kernel(
    const uint2* __restrict__ gbuf, const int* __restrict__ binBase,
    const int* __restrict__ rowptr, const int* __restrict__ cntp,
    int* __restrict__ eidx) {
  __shared__ int cur[8192];
  const int bin = blockIdx.x >> 2, s = blockIdx.x & 3;
  int n0, n1;
  bin_range(bin, n0, n1);
  const int rb = binBase[bin], re = binBase[bin + 1];
  const int len = re - rb;
  const int s0 = rb + (len * s) / 4;
  const int s1 = rb + (len * (s + 1)) / 4;
  for (int n = n0 + threadIdx.x; n < n1; n += 256) {
    int c = rowptr[n];
    if (s > 0) c += cntp[n];
    if (s > 1) c += cntp[NN + n];
    if (s > 2) c += cntp[2 * NN + n];
    cur[n - n0] = c;
  }
  __syncthreads();
  for (int r = s0 + threadIdx.x; r < s1; r += 256) {
    const uint2 rec = gbuf[r];
    const int p = atomicAdd(&cur[(int)rec.x - n0], 1);
    eidx[p] = (int)rec.y;
  }
}

// ---------------------------------------------------------------------------
// Fused SAGE layer: per 128-node block,
//   phase 0: stage X tile (global, swizzled LDS) -- issued first, hides latency
//   phase 1: each wave gather-means 32 nodes into swizzled LDS S tile
//   phase 2: MFMA GEMM  out = act(S @ Wl + bl + X @ Wr)  with K=64+64
// DOUT=64: 4 waves x 16-col tiles, 8 row-tiles each.
// DOUT=32: waves split 2 row-halves x 2 col-tiles, 4 row-tiles each.
// ---------------------------------------------------------------------------
template <int DOUT, bool RELU>
__global__ __launch_bounds__(256) void fused_layer_kernel(
    const int* __restrict__ rowptr, const int* __restrict__ eidx,
    const uint4* __restrict__ xin /* bf16 [NN][64] as uint4[NN][8] */,
    const float* __restrict__ Wl, const float* __restrict__ bl,
    const float* __restrict__ Wr, void* __restrict__ outv) {
  __shared__ u16 lS[128 * 64];  // gathered mean rows, swizzled (16 KB)
  __shared__ u16 lX[128 * 64];  // self rows, swizzled (16 KB)
  const int t = threadIdx.x;
  const int l = t & 63;
  const int wid = t >> 6;
  const int row0 = blockIdx.x * 128;

  // ---- phase 0: issue X tile staging (1024 uint4 chunks / 256 thr = 4) ----
  uint4 xreg[4];
#pragma unroll
  for (int i = 0; i < 4; ++i) {
    const int idx = i * 256 + t;
    const int r = idx >> 3, qq = idx & 7;
    xreg[i] = (row0 + r < NN) ? xin[(size_t)(row0 + r) * 8 + qq]
                              : make_uint4(0u, 0u, 0u, 0u);
  }

  // ---- B fragments (Wl, Wr) in VGPRs, fp32 -> bf16 ----
  const int n0 = (DOUT == 64 ? wid * 16 : (wid & 1) * 16) + (l & 15);
  const int kb = (l >> 4) * 8;
  short8 bfl[2], bfr[2];
#pragma unroll
  for (int kt = 0; kt < 2; ++kt) {
    union { u32 p[4]; short8 s; } ul, ur;
#pragma unroll
    for (int j = 0; j < 4; ++j) {
      const int k = kt * 32 + kb + 2 * j;
      ul.p[j] = cvtpk(Wl[(size_t)k * DOUT + n0], Wl[(size_t)(k + 1) * DOUT + n0]);
      ur.p[j] = cvtpk(Wr[(size_t)k * DOUT + n0], Wr[(size_t)(k + 1) * DOUT + n0]);
    }
    bfl[kt] = ul.s;
    bfr[kt] = ur.s;
  }
  const float bv = bl[n0];

  // write X tile (swizzle: byte ^= (row&7)<<4)
#pragma unroll
  for (int i = 0; i < 4; ++i) {
    const int idx = i * 256 + t;
    const int r = idx >> 3, qq = idx & 7;
    *reinterpret_cast<uint4*>(
        reinterpret_cast<char*>(lX) + ((r * 128 + qq * 16) ^ ((r & 7) << 4))) = xreg[i];
  }

  // ---- phase 1: gather-mean 32 nodes per wave into lS ----
  const int q = l & 7;   // 16B dim-slice
  const int h = l >> 3;  // edge slot 0..7
  for (int ln = wid * 32; ln < wid * 32 + 32; ++ln) {
    const int node = row0 + ln;
    int r0 = 0, r1 = 0;
    if (node < NN) {
      r0 = rowptr[node];
      r1 = rowptr[node + 1];
    }
    float s0 = 0.f, s1 = 0.f, s2 = 0.f, s3 = 0.f, s4 = 0.f, s5 = 0.f, s6 = 0.f,
          s7 = 0.f;
    for (int e = r0; e < r1; e += 16) {
      const int ee0 = e + h;
      const int ee1 = e + 8 + h;
      uint4 va = make_uint4(0u, 0u, 0u, 0u);
      uint4 vb = make_uint4(0u, 0u, 0u, 0u);
      if (ee0 < r1) va = xin[(size_t)eidx[ee0] * 8 + q];
      if (ee1 < r1) vb = xin[(size_t)eidx[ee1] * 8 + q];
      s0 += uasf(va.x << 16) + uasf(vb.x << 16);
      s1 += uasf(va.x & 0xffff0000u) + uasf(vb.x & 0xffff0000u);
      s2 += uasf(va.y << 16) + uasf(vb.y << 16);
      s3 += uasf(va.y & 0xffff0000u) + uasf(vb.y & 0xffff0000u);
      s4 += uasf(va.z << 16) + uasf(vb.z << 16);
      s5 += uasf(va.z & 0xffff0000u) + uasf(vb.z & 0xffff0000u);
      s6 += uasf(va.w << 16) + uasf(vb.w << 16);
      s7 += uasf(va.w & 0xffff0000u) + uasf(vb.w & 0xffff0000u);
    }
#pragma unroll
    for (int off = 8; off < 64; off <<= 1) {
      s0 += __shfl_xor(s0, off);
      s1 += __shfl_xor(s1, off);
      s2 += __shfl_xor(s2, off);
      s3 += __shfl_xor(s3, off);
      s4 += __shfl_xor(s4, off);
      s5 += __shfl_xor(s5, off);
      s6 += __shfl_xor(s6, off);
      s7 += __shfl_xor(s7, off);
    }
    if (h == 0) {
      const int deg = r1 - r0;
      const float inv = (deg > 0) ? (1.f / (float)deg) : 1.f;
      uint4 o;
      o.x = cvtpk(s0 * inv, s1 * inv);
      o.y = cvtpk(s2 * inv, s3 * inv);
      o.z = cvtpk(s4 * inv, s5 * inv);
      o.w = cvtpk(s6 * inv, s7 * inv);
      *reinterpret_cast<uint4*>(
          reinterpret_cast<char*>(lS) + ((ln * 128 + q * 16) ^ ((ln & 7) << 4))) = o;
    }
  }
  __syncthreads();

  // ---- phase 2: MFMA GEMM ----
  constexpr int NRT = (DOUT == 64) ? 8 : 4;
  const int rbase = (DOUT == 64) ? 0 : (wid >> 1) * 64;
  f32x4 acc[NRT];
#pragma unroll
  for (int rt = 0; rt < NRT; ++rt) {
    f32x4 z = {0.f, 0.f, 0.f, 0.f};
    acc[rt] = z;
  }
#pragma unroll
  for (int kt = 0; kt < 2; ++kt) {
#pragma unroll
    for (int rt = 0; rt < NRT; ++rt) {
      const int row = rbase + rt * 16 + (l & 15);
      const int boff = (row * 128 + (kt * 4 + (l >> 4)) * 16) ^ ((row & 7) << 4);
      const short8 aS =
          *reinterpret_cast<const short8*>(reinterpret_cast<const char*>(lS) + boff);
      acc[rt] = __builtin_amdgcn_mfma_f32_16x16x32_bf16(aS, bfl[kt], acc[rt], 0, 0, 0);
      const short8 aX =
          *reinterpret_cast<const short8*>(reinterpret_cast<const char*>(lX) + boff);
      acc[rt] = __builtin_amdgcn_mfma_f32_16x16x32_bf16(aX, bfr[kt], acc[rt], 0, 0, 0);
    }
  }

  // ---- epilogue (m89 C/D mapping: col = l&15, row = (l>>4)*4 + r) ----
#pragma unroll
  for (int rt = 0; rt < NRT; ++rt) {
#pragma unroll
    for (int r = 0; r < 4; ++r) {
      const int grow = row0 + rbase + rt * 16 + (l >> 4) * 4 + r;
      if (grow < NN) {
        float o = acc[rt][r] + bv;
        if (RELU) o = fmaxf(o, 0.f);
        if (DOUT == 64)
          ((u16*)outv)[(size_t)grow * 64 + n0] = f2bf(o);
        else
          ((float*)outv)[(size_t)grow * 32 + n0] = o;
      }
    }
  }
}

// ---------------------------------------------------------------------------
extern "C" void kernel_launch(void* const* d_in, const int* in_sizes, int n_in,
                              void* d_out, int out_size, void* d_ws, size_t ws_size,
                              hipStream_t stream) {
  const float* product_x = (const float*)d_in[0];
  const float* user_emb = (const float*)d_in[1];
  const float* brand_emb = (const float*)d_in[2];
  const float* cat_emb = (const float*)d_in[3];
  const float* shop_emb = (const float*)d_in[4];
  const float* proj_W = (const float*)d_in[5];
  const float* proj_b = (const float*)d_in[6];
  const float* c1_Wl = (const float*)d_in[7];
  const float* c1_bl = (const float*)d_in[8];
  const float* c1_Wr = (const float*)d_in[9];
  const float* c2_Wl = (const float*)d_in[10];
  const float* c2_bl = (const float*)d_in[11];
  const float* c2_Wr = (const float*)d_in[12];
  const int* pb_src = (const int*)d_in[13];
  const int* pb_dst = (const int*)d_in[14];
  const int* pc_src = (const int*)d_in[15];
  const int* pc_dst = (const int*)d_in[16];
  const int* ps_src = (const int*)d_in[17];
  const int* ps_dst = (const int*)d_in[18];
  const int* up_src = (const int*)d_in[19];
  const int* up_dst = (const int*)d_in[20];
  const int nPB = in_sizes[13], nPC = in_sizes[15], nPS = in_sizes[17], nUP = in_sizes[19];
  const int nE = nPB + nPC + nPS + nUP;
  const int nD = 2 * nE;

  // workspace layout (bf16 tables as u16/u32 views)
  u16* xb = (u16*)d_ws;                          // [NN*64] bf16
  u16* out1 = xb + (size_t)NN * 64;              // [NN*64] bf16
  u16* scratch = out1 + (size_t)NN * 64;         // [NN*64] region (gbuf scratch)
  int* eidx = (int*)(scratch + (size_t)NN * 64); // [nD]
  int* rowptr = eidx + nD;                       // [NN+1]
  int* blockSums = rowptr + (NN + 1);            // [512]
  int* binCnt = blockSums + 512;                 // [128]
  int* binBase = binCnt + 128;                   // [NBINS+1]
  int* gcur = binBase + 128;                     // [NBINS*16] padded
  // aliased scratch (dead before their regions' first real write):
  uint2* gbuf = (uint2*)scratch;  // [nD] 28.8MB <= 39.4MB; dead after fill_scatter
  int* cntp = (int*)out1;         // [4*NN] 4.9MB; dead until fused layer1 writes out1

  hipMemsetAsync(binCnt, 0, 128 * sizeof(int), stream);

  bin_count_kernel<<<512, 256, 0, stream>>>(pb_src, pb_dst, pc_src, pc_dst, ps_src, ps_dst,
                                            up_src, up_dst, nPB, nPC, nPS, nD, binCnt);
  bin_scan_kernel<<<1, 128, 0, stream>>>(binCnt, binBase, gcur);
  bin_scatter_kernel<<<512, 256, 0, stream>>>(pb_src, pb_dst, pc_src, pc_dst, ps_src, ps_dst,
                                              up_src, up_dst, nPB, nPC, nPS, nD, gbuf, gcur);
  count_nodes_kernel<<<NBINS * 4, 256, 0, stream>>>(gbuf, binBase, cntp);

  const int nb = (NN + 1023) / 1024;  // 301
  scan1_kernel<<<nb, 256, 0, stream>>>(cntp, blockSums, NN);
  scan2_kernel<<<1, 512, 0, stream>>>(blockSums, nb);
  scan3_kernel<<<nb, 256, 0, stream>>>(cntp, blockSums, rowptr, NN);

  fill_scatter_kernel<<<NBINS * 4, 256, 0, stream>>>(gbuf, binBase, rowptr, cntp, eidx);

  proj_mfma_kernel<<<(NP + 127) / 128, 256, 0, stream>>>(product_x, proj_W, proj_b, xb);
  cvt_emb_kernel<<<((NU + NBR + NCAT + NSH) * 16 + 255) / 256, 256, 0, stream>>>(
      user_emb, brand_emb, cat_emb, shop_emb, xb);

  const int nBlk = (NN + 127) / 128;  // 2407
  // Layer 1: gather+GEMM fused (xb -> out1, relu)
  fused_layer_kernel<64, true><<<nBlk, 256, 0, stream>>>(
      rowptr, eidx, (const uint4*)xb, c1_Wl, c1_bl, c1_Wr, out1);
  // Layer 2: gather+GEMM fused (out1 -> d_out, no relu, fp32 out)
  fused_layer_kernel<32, false><<<nBlk, 256, 0, stream>>>(
      rowptr, eidx, (const uint4*)out1, c2_Wl, c2_bl, c2_Wr, d_out);
}

// Round 12
// 535.512 us; speedup vs baseline: 4.0280x; 4.0280x over previous
//
#include <hip/hip_runtime.h>

#define NP 200000
#define NU 100000
#define NBR 5000
#define NCAT 2000
#define NSH 1000
#define NN (NP + NU + NBR + NCAT + NSH) /* 308000 */
#define OFF_U NP
#define OFF_B (NP + NU)
#define OFF_C (NP + NU + NBR)
#define OFF_S (NP + NU + NBR + NCAT)

#define NBINS 67 /* class-aware node bins: 25 P(8192) + 13 U(8192) + 5 B(1024) + 8 C(256) + 16 S(64) */

typedef unsigned short u16;
typedef unsigned int u32;
typedef __attribute__((ext_vector_type(8))) short short8;
typedef __attribute__((ext_vector_type(4))) float f32x4;

__device__ __forceinline__ u16 f2bf(float f) {
  union { float f; unsigned u; } v;
  v.f = f;
  unsigned r = (v.u + 0x7fffu + ((v.u >> 16) & 1u)) >> 16;  // RNE
  return (u16)r;
}
__device__ __forceinline__ float uasf(u32 u) {
  union { u32 u; float f; } v;
  v.u = u;
  return v.f;
}
// pack 2 fp32 -> 2 bf16 (RNE) in one instr
__device__ __forceinline__ u32 cvtpk(float lo, float hi) {
  u32 r;
  asm("v_cvt_pk_bf16_f32 %0, %1, %2" : "=v"(r) : "v"(lo), "v"(hi));
  return r;
}

// node -> bin (class-aware ranges; each bin spans <= 8192 nodes)
__device__ __forceinline__ int bin_of(int a) {
  if (a < OFF_U) return a >> 13;
  if (a < OFF_B) return 25 + ((a - OFF_U) >> 13);
  if (a < OFF_C) return 38 + ((a - OFF_B) >> 10);
  if (a < OFF_S) return 43 + ((a - OFF_C) >> 8);
  return 51 + ((a - OFF_S) >> 6);
}
__device__ __forceinline__ void bin_range(int bin, int& n0, int& n1) {
  if (bin < 25) {
    n0 = bin << 13; n1 = min(n0 + 8192, OFF_U);
  } else if (bin < 38) {
    n0 = OFF_U + ((bin - 25) << 13); n1 = min(n0 + 8192, OFF_B);
  } else if (bin < 43) {
    n0 = OFF_B + ((bin - 38) << 10); n1 = min(n0 + 1024, OFF_C);
  } else if (bin < 51) {
    n0 = OFF_C + ((bin - 43) << 8); n1 = min(n0 + 256, OFF_S);
  } else {
    n0 = OFF_S + ((bin - 51) << 6); n1 = min(n0 + 64, NN);
  }
}

// ---------------------------------------------------------------------------
// MFMA projection: xb[r][c] = bf16(relu(px[r][:] @ W[:][c] + b[c])), r<NP.
// ---------------------------------------------------------------------------
__global__ __launch_bounds__(256) void proj_mfma_kernel(
    const float* __restrict__ px, const float* __restrict__ W,
    const float* __restrict__ bias, u16* __restrict__ xb) {
  __shared__ u16 lA[2][128 * 32];  // 8 KB per buffer, bf16, swizzled
  const int t = threadIdx.x;
  const int l = t & 63;
  const int wid = t >> 6;
  const int row0 = blockIdx.x * 128;

  const int n0 = wid * 16 + (l & 15);
  const int kb = (l >> 4) * 8;
  short8 bf[12];
#pragma unroll
  for (int kt = 0; kt < 12; ++kt) {
    union { u32 p[4]; short8 s; } uu;
#pragma unroll
    for (int j = 0; j < 4; ++j) {
      const float lo = W[(size_t)(kt * 32 + kb + 2 * j) * 64 + n0];
      const float hi = W[(size_t)(kt * 32 + kb + 2 * j + 1) * 64 + n0];
      uu.p[j] = cvtpk(lo, hi);
    }
    bf[kt] = uu.s;
  }
  const float bv = bias[n0];

  f32x4 acc[8];
#pragma unroll
  for (int rt = 0; rt < 8; ++rt) {
    f32x4 z = {0.f, 0.f, 0.f, 0.f};
    acc[rt] = z;
  }

  const int fr_base = (((l & 15) * 64 + (l >> 4) * 16)) ^ ((l & 7) << 4);

  float4 sreg[4];
#pragma unroll
  for (int i = 0; i < 4; ++i) {
    const int qi = t + 256 * i;
    const int r = qi >> 3, q = qi & 7;
    const int grow = row0 + r;
    sreg[i] = (grow < NP) ? *reinterpret_cast<const float4*>(px + (size_t)grow * 384 + q * 4)
                          : make_float4(0.f, 0.f, 0.f, 0.f);
  }
#pragma unroll
  for (int i = 0; i < 4; ++i) {
    const int qi = t + 256 * i;
    const int r = qi >> 3, q = qi & 7;
    const int a16 = (((r * 64 + q * 8)) ^ ((r & 7) << 4)) >> 1;
    const u32 p0 = cvtpk(sreg[i].x, sreg[i].y);
    const u32 p1 = cvtpk(sreg[i].z, sreg[i].w);
    *reinterpret_cast<uint2*>(&lA[0][a16]) = make_uint2(p0, p1);
  }

#pragma unroll
  for (int kt = 0; kt < 12; ++kt) {
    const int cur = kt & 1;
    if (kt + 1 < 12) {
#pragma unroll
      for (int i = 0; i < 4; ++i) {
        const int qi = t + 256 * i;
        const int r = qi >> 3, q = qi & 7;
        const int grow = row0 + r;
        sreg[i] = (grow < NP)
                      ? *reinterpret_cast<const float4*>(px + (size_t)grow * 384 +
                                                         (kt + 1) * 32 + q * 4)
                      : make_float4(0.f, 0.f, 0.f, 0.f);
      }
    }
    __syncthreads();
#pragma unroll
    for (int rt = 0; rt < 8; ++rt) {
      const short8 af =
          *reinterpret_cast<const short8*>(&lA[cur][(fr_base + rt * 1024) >> 1]);
      acc[rt] = __builtin_amdgcn_mfma_f32_16x16x32_bf16(af, bf[kt], acc[rt], 0, 0, 0);
    }
    if (kt + 1 < 12) {
#pragma unroll
      for (int i = 0; i < 4; ++i) {
        const int qi = t + 256 * i;
        const int r = qi >> 3, q = qi & 7;
        const int a16 = (((r * 64 + q * 8)) ^ ((r & 7) << 4)) >> 1;
        const u32 p0 = cvtpk(sreg[i].x, sreg[i].y);
        const u32 p1 = cvtpk(sreg[i].z, sreg[i].w);
        *reinterpret_cast<uint2*>(&lA[cur ^ 1][a16]) = make_uint2(p0, p1);
      }
    }
  }

#pragma unroll
  for (int rt = 0; rt < 8; ++rt) {
#pragma unroll
    for (int r = 0; r < 4; ++r) {
      const int grow = row0 + rt * 16 + (l >> 4) * 4 + r;
      if (grow < NP)
        xb[(size_t)grow * 64 + n0] = f2bf(fmaxf(acc[rt][r] + bv, 0.f));
    }
  }
}

// ---------------------------------------------------------------------------
// Fused fp32->bf16 conversion of all 4 embedding tables into xb.
// ---------------------------------------------------------------------------
__global__ void cvt_emb_kernel(const float* __restrict__ ue, const float* __restrict__ be,
                               const float* __restrict__ ce, const float* __restrict__ se,
                               u16* __restrict__ xb) {
  const int i = blockIdx.x * 256 + threadIdx.x;
  const int totalQ = (NU + NBR + NCAT + NSH) * 16;
  if (i >= totalQ) return;
  const int row = i >> 4, q = i & 15;
  const float* src;
  int lrow;
  if (row < NU) {
    src = ue; lrow = row;
  } else if (row < NU + NBR) {
    src = be; lrow = row - NU;
  } else if (row < NU + NBR + NCAT) {
    src = ce; lrow = row - NU - NBR;
  } else {
    src = se; lrow = row - NU - NBR - NCAT;
  }
  const float4 v = reinterpret_cast<const float4*>(src)[(size_t)lrow * 16 + q];
  ushort4 o;
  o.x = f2bf(v.x);
  o.y = f2bf(v.y);
  o.z = f2bf(v.z);
  o.w = f2bf(v.w);
  reinterpret_cast<ushort4*>(xb + (size_t)(OFF_U + row) * 64)[q] = o;
}

// ---------------------------------------------------------------------------
// Directed-entry decode. i in [0, 2*nE).
// ---------------------------------------------------------------------------
__device__ __forceinline__ void decode_edge(
    int i, const int* pbs, const int* pbd, const int* pcs, const int* pcd,
    const int* pss, const int* psd, const int* ups, const int* upd,
    int nPB, int nPC, int nPS, int& a, int& b) {
  const int d = i & 1;
  int eu = i >> 1;
  int a0, b0;
  if (eu < nPB) {
    a0 = pbs[eu]; b0 = pbd[eu] + OFF_B;
  } else {
    eu -= nPB;
    if (eu < nPC) {
      a0 = pcs[eu]; b0 = pcd[eu] + OFF_C;
    } else {
      eu -= nPC;
      if (eu < nPS) {
        a0 = pss[eu]; b0 = psd[eu] + OFF_S;
      } else {
        eu -= nPS;
        a0 = ups[eu] + OFF_U; b0 = upd[eu];
      }
    }
  }
  a = d ? b0 : a0;
  b = d ? a0 : b0;
}

#define EDGE_ARGS const int* __restrict__ pbs, const int* __restrict__ pbd, \
                  const int* __restrict__ pcs, const int* __restrict__ pcd, \
                  const int* __restrict__ pss, const int* __restrict__ psd, \
                  const int* __restrict__ ups, const int* __restrict__ upd, \
                  int nPB, int nPC, int nPS, int nD
#define EDGE_PASS pbs, pbd, pcs, pcd, pss, psd, ups, upd, nPB, nPC, nPS

// ---------------------------------------------------------------------------
// 1. Global histogram of directed entries per node-bin (34k global atomics).
// ---------------------------------------------------------------------------
__global__ __launch_bounds__(256) void bin_count_kernel(EDGE_ARGS,
                                                        int* __restrict__ binCnt) {
  __shared__ int lh[NBINS];
  const int t = threadIdx.x;
  if (t < NBINS) lh[t] = 0;
  __syncthreads();
  for (int i = blockIdx.x * 256 + t; i < nD; i += gridDim.x * 256) {
    int a, b;
    decode_edge(i, EDGE_PASS, a, b);
    (void)b;
    atomicAdd(&lh[bin_of(a)], 1);
  }
  __syncthreads();
  if (t < NBINS && lh[t] > 0) atomicAdd(&binCnt[t], lh[t]);
}

// 2. Tiny scan: binCnt[NBINS] -> binBase[NBINS+1]; init gcur.
__global__ void bin_scan_kernel(const int* __restrict__ binCnt, int* __restrict__ binBase,
                                int* __restrict__ gcur) {
  __shared__ int base[NBINS + 1];
  if (threadIdx.x == 0) {
    int run = 0;
    for (int b = 0; b < NBINS; ++b) {
      base[b] = run;
      run += binCnt[b];
    }
    base[NBINS] = run;
  }
  __syncthreads();
  if (threadIdx.x <= NBINS) binBase[threadIdx.x] = base[threadIdx.x];
  if (threadIdx.x < NBINS) gcur[threadIdx.x * 16] = base[threadIdx.x];
}

// ---------------------------------------------------------------------------
// 3. Two-phase block binning by node-bin: LDS hist -> one gcur reserve per
//    bin per block -> re-decode (L2-hot) -> grouped coalesced record writes.
// ---------------------------------------------------------------------------
__global__ __launch_bounds__(256) void bin_scatter_kernel(EDGE_ARGS,
                                                          uint2* __restrict__ gbuf,
                                                          int* __restrict__ gcur) {
  __shared__ int lh[NBINS];
  __shared__ int gb[NBINS];
  __shared__ int ofs[NBINS];
  const int t = threadIdx.x;
  const int per = (nD + gridDim.x - 1) / gridDim.x;
  const int start = blockIdx.x * per;
  const int end = (start + per < nD) ? (start + per) : nD;

  if (t < NBINS) {
    lh[t] = 0;
    ofs[t] = 0;
  }
  __syncthreads();
  for (int i = start + t; i < end; i += 256) {
    int a, b;
    decode_edge(i, EDGE_PASS, a, b);
    (void)b;
    atomicAdd(&lh[bin_of(a)], 1);
  }
  __syncthreads();
  if (t < NBINS && lh[t] > 0) gb[t] = atomicAdd(&gcur[t * 16], lh[t]);
  __syncthreads();
  for (int i = start + t; i < end; i += 256) {
    int a, b;
    decode_edge(i, EDGE_PASS, a, b);
    const int bb = bin_of(a);
    const int d = atomicAdd(&ofs[bb], 1);
    gbuf[gb[bb] + d] = make_uint2((u32)a, (u32)b);
  }
}

// ---------------------------------------------------------------------------
// 4. Per-bin-slice node counting: LDS counters, coalesced partial writes.
// ---------------------------------------------------------------------------
__global__ __launch_bounds__(256) void count_nodes_kernel(
    const uint2* __restrict__ gbuf, const int* __restrict__ binBase,
    int* __restrict__ cntp) {
  __shared__ int cnt[8192];
  const int bin = blockIdx.x >> 2, s = blockIdx.x & 3;
  int n0, n1;
  bin_range(bin, n0, n1);
  const int rb = binBase[bin], re = binBase[bin + 1];
  const int len = re - rb;
  const int s0 = rb + (len * s) / 4;
  const int s1 = rb + (len * (s + 1)) / 4;
  for (int i = threadIdx.x; i < 8192; i += 256) cnt[i] = 0;
  __syncthreads();
  for (int r = s0 + threadIdx.x; r < s1; r += 256)
    atomicAdd(&cnt[(int)gbuf[r].x - n0], 1);
  __syncthreads();
  for (int n = n0 + threadIdx.x; n < n1; n += 256)
    cntp[s * NN + n] = cnt[n - n0];
}

// 3-kernel exclusive scan over sum of 4 partials -> rowptr[NN+1]
__global__ __launch_bounds__(256) void scan1_kernel(const int* __restrict__ cntp,
                                                    int* __restrict__ blockSums, int n) {
  __shared__ int sdata[256];
  const int base = blockIdx.x * 1024;
  int s = 0;
  for (int i = threadIdx.x; i < 1024; i += 256) {
    int idx = base + i;
    if (idx < n)
      s += cntp[idx] + cntp[NN + idx] + cntp[2 * NN + idx] + cntp[3 * NN + idx];
  }
  sdata[threadIdx.x] = s;
  __syncthreads();
  for (int off = 128; off > 0; off >>= 1) {
    if (threadIdx.x < off) sdata[threadIdx.x] += sdata[threadIdx.x + off];
    __syncthreads();
  }
  if (threadIdx.x == 0) blockSums[blockIdx.x] = sdata[0];
}

__global__ __launch_bounds__(512) void scan2_kernel(int* __restrict__ blockSums, int nb) {
  __shared__ int sd[512];
  const int t = threadIdx.x;
  const int v = (t < nb) ? blockSums[t] : 0;
  sd[t] = v;
  __syncthreads();
  for (int off = 1; off < 512; off <<= 1) {
    int add = (t >= off) ? sd[t - off] : 0;
    __syncthreads();
    sd[t] += add;
    __syncthreads();
  }
  if (t < nb) blockSums[t] = sd[t] - v;  // exclusive
}

__global__ __launch_bounds__(256) void scan3_kernel(const int* __restrict__ cntp,
                                                    const int* __restrict__ blockSums,
                                                    int* __restrict__ rowptr, int n) {
  __shared__ int wsum[4];
  const int base = blockIdx.x * 1024;
  const int t = threadIdx.x, lane = t & 63, wid = t >> 6;
  const int idx0 = base + t * 4;
  int v[4];
#pragma unroll
  for (int j = 0; j < 4; ++j) {
    int idx = idx0 + j;
    v[j] = (idx < n)
               ? cntp[idx] + cntp[NN + idx] + cntp[2 * NN + idx] + cntp[3 * NN + idx]
               : 0;
  }
  const int s = v[0] + v[1] + v[2] + v[3];
  int incl = s;
  for (int off = 1; off < 64; off <<= 1) {
    int tt = __shfl_up(incl, off);
    if (lane >= off) incl += tt;
  }
  if (lane == 63) wsum[wid] = incl;
  __syncthreads();
  int wOff = 0;
#pragma unroll
  for (int w = 0; w < 4; ++w)
    if (w < wid) wOff += wsum[w];
  int run = blockSums[blockIdx.x] + wOff + (incl - s);
#pragma unroll
  for (int j = 0; j < 4; ++j) {
    int idx = idx0 + j;
    if (idx < n) {
      rowptr[idx] = run;
      run += v[j];
      if (idx == n - 1) rowptr[n] = run;
    }
  }
}

// ---------------------------------------------------------------------------
// 6. Final fill: LDS cursor, LDS-atomic position assignment, windowed scatter.
// ---------------------------------------------------------------------------
__global__ __launch_bounds__(256) void fill_scatter_kernel(
    const uint2* __restrict__ gbuf, const int* __restrict__ binBase,
    const int* __restrict__ rowptr, const int* __restrict__ cntp,
    int* __restrict__ eidx) {
  __shared__ int cur[8192];
  const int bin = blockIdx.x >> 2, s = blockIdx.x & 3;
  int n0, n1;
  bin_range(bin, n0, n1);
  const int rb = binBase[bin], re = binBase[bin + 1];
  const int len = re - rb;
  const int s0 = rb + (len * s) / 4;
  const int s1 = rb + (len * (s + 1)) / 4;
  for (int n = n0 + threadIdx.x; n < n1; n += 256) {
    int c = rowptr[n];
    if (s > 0) c += cntp[n];
    if (s > 1) c += cntp[NN + n];
    if (s > 2) c += cntp[2 * NN + n];
    cur[n - n0] = c;
  }
  __syncthreads();
  for (int r = s0 + threadIdx.x; r < s1; r += 256) {
    const uint2 rec = gbuf[r];
    const int p = atomicAdd(&cur[(int)rec.x - n0], 1);
    eidx[p] = (int)rec.y;
  }
}

// ---------------------------------------------------------------------------
// Gather-mean (high-TLP, grid-stride): sout[node][:] = bf16(mean of nbr rows).
// 8 lanes per row (uint4); 16 edges in flight; exec-masked tails; shfl reduce.
// ---------------------------------------------------------------------------
__global__ __launch_bounds__(256) void gather_mean_kernel(
    const int* __restrict__ rowptr, const int* __restrict__ eidx,
    const uint4* __restrict__ xin, uint4* __restrict__ sout) {
  const int lane = threadIdx.x & 63;
  const int q = lane & 7;   // 16B dim-slice within the 128B row
  const int h = lane >> 3;  // edge slot 0..7
  const int wid0 = blockIdx.x * 4 + (threadIdx.x >> 6);
  const int nW = gridDim.x * 4;
  for (int node = wid0; node < NN; node += nW) {
    const int r0 = rowptr[node], r1 = rowptr[node + 1];
    float s0 = 0.f, s1 = 0.f, s2 = 0.f, s3 = 0.f, s4 = 0.f, s5 = 0.f, s6 = 0.f,
          s7 = 0.f;
    for (int e = r0; e < r1; e += 16) {
      const int ee0 = e + h;
      const int ee1 = e + 8 + h;
      uint4 va = make_uint4(0u, 0u, 0u, 0u);
      uint4 vb = make_uint4(0u, 0u, 0u, 0u);
      if (ee0 < r1) va = xin[(size_t)eidx[ee0] * 8 + q];  // exec-masked load
      if (ee1 < r1) vb = xin[(size_t)eidx[ee1] * 8 + q];
      s0 += uasf(va.x << 16) + uasf(vb.x << 16);
      s1 += uasf(va.x & 0xffff0000u) + uasf(vb.x & 0xffff0000u);
      s2 += uasf(va.y << 16) + uasf(vb.y << 16);
      s3 += uasf(va.y & 0xffff0000u) + uasf(vb.y & 0xffff0000u);
      s4 += uasf(va.z << 16) + uasf(vb.z << 16);
      s5 += uasf(va.z & 0xffff0000u) + uasf(vb.z & 0xffff0000u);
      s6 += uasf(va.w << 16) + uasf(vb.w << 16);
      s7 += uasf(va.w & 0xffff0000u) + uasf(vb.w & 0xffff0000u);
    }
#pragma unroll
    for (int off = 8; off < 64; off <<= 1) {
      s0 += __shfl_xor(s0, off);
      s1 += __shfl_xor(s1, off);
      s2 += __shfl_xor(s2, off);
      s3 += __shfl_xor(s3, off);
      s4 += __shfl_xor(s4, off);
      s5 += __shfl_xor(s5, off);
      s6 += __shfl_xor(s6, off);
      s7 += __shfl_xor(s7, off);
    }
    if (h == 0) {
      const int deg = r1 - r0;
      const float inv = (deg > 0) ? (1.f / (float)deg) : 1.f;
      uint4 o;
      o.x = cvtpk(s0 * inv, s1 * inv);
      o.y = cvtpk(s2 * inv, s3 * inv);
      o.z = cvtpk(s4 * inv, s5 * inv);
      o.w = cvtpk(s6 * inv, s7 * inv);
      sout[(size_t)node * 8 + q] = o;
    }
  }
}

// ---------------------------------------------------------------------------
// MFMA layer GEMM: out = act(S @ Wl + bl + X @ Wr), S,X bf16 [NN][64].
// Stage S,X tiles into swizzled LDS; Wl,Wr frags (bf16) in VGPRs; K=64 each.
// DOUT=64: 4 waves x 16-col tiles, 8 row-tiles. DOUT=32: 2x2 split, 4 tiles.
// (GEMM structure verified correct in round-11's fused kernel.)
// ---------------------------------------------------------------------------
template <int DOUT, bool RELU>
__global__ __launch_bounds__(256) void layer_mfma_kernel(
    const uint4* __restrict__ S, const uint4* __restrict__ X,
    const float* __restrict__ Wl, const float* __restrict__ bl,
    const float* __restrict__ Wr, void* __restrict__ outv) {
  __shared__ u16 lS[128 * 64];  // 16 KB, swizzled
  __shared__ u16 lX[128 * 64];  // 16 KB, swizzled
  const int t = threadIdx.x;
  const int l = t & 63;
  const int wid = t >> 6;
  const int row0 = blockIdx.x * 128;

  // issue staging loads first (hide under W-frag setup)
  uint4 sreg[4], xreg[4];
#pragma unroll
  for (int i = 0; i < 4; ++i) {
    const int idx = i * 256 + t;
    const int r = idx >> 3, qq = idx & 7;
    const bool ok = (row0 + r < NN);
    sreg[i] = ok ? S[(size_t)(row0 + r) * 8 + qq] : make_uint4(0u, 0u, 0u, 0u);
    xreg[i] = ok ? X[(size_t)(row0 + r) * 8 + qq] : make_uint4(0u, 0u, 0u, 0u);
  }

  // B fragments (Wl, Wr) in VGPRs, fp32 -> bf16
  const int n0 = (DOUT == 64 ? wid * 16 : (wid & 1) * 16) + (l & 15);
  const int kb = (l >> 4) * 8;
  short8 bfl[2], bfr[2];
#pragma unroll
  for (int kt = 0; kt < 2; ++kt) {
    union { u32 p[4]; short8 s; } ul, ur;
#pragma unroll
    for (int j = 0; j < 4; ++j) {
      const int k = kt * 32 + kb + 2 * j;
      ul.p[j] = cvtpk(Wl[(size_t)k * DOUT + n0], Wl[(size_t)(k + 1) * DOUT + n0]);
      ur.p[j] = cvtpk(Wr[(size_t)k * DOUT + n0], Wr[(size_t)(k + 1) * DOUT + n0]);
    }
    bfl[kt] = ul.s;
    bfr[kt] = ur.s;
  }
  const float bv = bl[n0];

  // write tiles (swizzle: byte ^= (row&7)<<4)
#pragma unroll
  for (int i = 0; i < 4; ++i) {
    const int idx = i * 256 + t;
    const int r = idx >> 3, qq = idx & 7;
    const int boff = (r * 128 + qq * 16) ^ ((r & 7) << 4);
    *reinterpret_cast<uint4*>(reinterpret_cast<char*>(lS) + boff) = sreg[i];
    *reinterpret_cast<uint4*>(reinterpret_cast<char*>(lX) + boff) = xreg[i];
  }
  __syncthreads();

  constexpr int NRT = (DOUT == 64) ? 8 : 4;
  const int rbase = (DOUT == 64) ? 0 : (wid >> 1) * 64;
  f32x4 acc[NRT];
#pragma unroll
  for (int rt = 0; rt < NRT; ++rt) {
    f32x4 z = {0.f, 0.f, 0.f, 0.f};
    acc[rt] = z;
  }
#pragma unroll
  for (int kt = 0; kt < 2; ++kt) {
#pragma unroll
    for (int rt = 0; rt < NRT; ++rt) {
      const int row = rbase + rt * 16 + (l & 15);
      const int boff = (row * 128 + (kt * 4 + (l >> 4)) * 16) ^ ((row & 7) << 4);
      const short8 aS =
          *reinterpret_cast<const short8*>(reinterpret_cast<const char*>(lS) + boff);
      acc[rt] = __builtin_amdgcn_mfma_f32_16x16x32_bf16(aS, bfl[kt], acc[rt], 0, 0, 0);
      const short8 aX =
          *reinterpret_cast<const short8*>(reinterpret_cast<const char*>(lX) + boff);
      acc[rt] = __builtin_amdgcn_mfma_f32_16x16x32_bf16(aX, bfr[kt], acc[rt], 0, 0, 0);
    }
  }

  // epilogue (m89 C/D mapping: col = l&15, row = (l>>4)*4 + r)
#pragma unroll
  for (int rt = 0; rt < NRT; ++rt) {
#pragma unroll
    for (int r = 0; r < 4; ++r) {
      const int grow = row0 + rbase + rt * 16 + (l >> 4) * 4 + r;
      if (grow < NN) {
        float o = acc[rt][r] + bv;
        if (RELU) o = fmaxf(o, 0.f);
        if (DOUT == 64)
          ((u16*)outv)[(size_t)grow * 64 + n0] = f2bf(o);
        else
          ((float*)outv)[(size_t)grow * 32 + n0] = o;
      }
    }
  }
}

// ---------------------------------------------------------------------------
extern "C" void kernel_launch(void* const* d_in, const int* in_sizes, int n_in,
                              void* d_out, int out_size, void* d_ws, size_t ws_size,
                              hipStream_t stream) {
  const float* product_x = (const float*)d_in[0];
  const float* user_emb = (const float*)d_in[1];
  const float* brand_emb = (const float*)d_in[2];
  const float* cat_emb = (const float*)d_in[3];
  const float* shop_emb = (const float*)d_in[4];
  const float* proj_W = (const float*)d_in[5];
  const float* proj_b = (const float*)d_in[6];
  const float* c1_Wl = (const float*)d_in[7];
  const float* c1_bl = (const float*)d_in[8];
  const float* c1_Wr = (const float*)d_in[9];
  const float* c2_Wl = (const float*)d_in[10];
  const float* c2_bl = (const float*)d_in[11];
  const float* c2_Wr = (const float*)d_in[12];
  const int* pb_src = (const int*)d_in[13];
  const int* pb_dst = (const int*)d_in[14];
  const int* pc_src = (const int*)d_in[15];
  const int* pc_dst = (const int*)d_in[16];
  const int* ps_src = (const int*)d_in[17];
  const int* ps_dst = (const int*)d_in[18];
  const int* up_src = (const int*)d_in[19];
  const int* up_dst = (const int*)d_in[20];
  const int nPB = in_sizes[13], nPC = in_sizes[15], nPS = in_sizes[17], nUP = in_sizes[19];
  const int nE = nPB + nPC + nPS + nUP;
  const int nD = 2 * nE;

  // workspace layout (bf16 tables as u16/u32 views)
  u16* xb = (u16*)d_ws;                          // [NN*64] bf16
  u16* out1 = xb + (size_t)NN * 64;              // [NN*64] bf16
  u16* sbuf = out1 + (size_t)NN * 64;            // [NN*64] bf16 (reused both layers)
  int* eidx = (int*)(sbuf + (size_t)NN * 64);    // [nD]
  int* rowptr = eidx + nD;                       // [NN+1]
  int* blockSums = rowptr + (NN + 1);            // [512]
  int* binCnt = blockSums + 512;                 // [128]
  int* binBase = binCnt + 128;                   // [NBINS+1]
  int* gcur = binBase + 128;                     // [NBINS*16] padded
  // aliased scratch (dead before their regions' first real write):
  uint2* gbuf = (uint2*)sbuf;  // [nD] 28.8MB <= 39.4MB; dead until gather1 writes sbuf
  int* cntp = (int*)out1;      // [4*NN] 4.9MB; dead until layer1 writes out1

  hipMemsetAsync(binCnt, 0, 128 * sizeof(int), stream);

  bin_count_kernel<<<512, 256, 0, stream>>>(pb_src, pb_dst, pc_src, pc_dst, ps_src, ps_dst,
                                            up_src, up_dst, nPB, nPC, nPS, nD, binCnt);
  bin_scan_kernel<<<1, 128, 0, stream>>>(binCnt, binBase, gcur);
  bin_scatter_kernel<<<512, 256, 0, stream>>>(pb_src, pb_dst, pc_src, pc_dst, ps_src, ps_dst,
                                              up_src, up_dst, nPB, nPC, nPS, nD, gbuf, gcur);
  count_nodes_kernel<<<NBINS * 4, 256, 0, stream>>>(gbuf, binBase, cntp);

  const int nb = (NN + 1023) / 1024;  // 301
  scan1_kernel<<<nb, 256, 0, stream>>>(cntp, blockSums, NN);
  scan2_kernel<<<1, 512, 0, stream>>>(blockSums, nb);
  scan3_kernel<<<nb, 256, 0, stream>>>(cntp, blockSums, rowptr, NN);

  fill_scatter_kernel<<<NBINS * 4, 256, 0, stream>>>(gbuf, binBase, rowptr, cntp, eidx);

  proj_mfma_kernel<<<(NP + 127) / 128, 256, 0, stream>>>(product_x, proj_W, proj_b, xb);
  cvt_emb_kernel<<<((NU + NBR + NCAT + NSH) * 16 + 255) / 256, 256, 0, stream>>>(
      user_emb, brand_emb, cat_emb, shop_emb, xb);

  const int nBlk = (NN + 127) / 128;  // 2407
  // Layer 1
  gather_mean_kernel<<<4096, 256, 0, stream>>>(rowptr, eidx, (const uint4*)xb,
                                               (uint4*)sbuf);
  layer_mfma_kernel<64, true><<<nBlk, 256, 0, stream>>>(
      (const uint4*)sbuf, (const uint4*)xb, c1_Wl, c1_bl, c1_Wr, out1);
  // Layer 2
  gather_mean_kernel<<<4096, 256, 0, stream>>>(rowptr, eidx, (const uint4*)out1,
                                               (uint4*)sbuf);
  layer_mfma_kernel<32, false><<<nBlk, 256, 0, stream>>>(
      (const uint4*)sbuf, (const uint4*)out1, c2_Wl, c2_bl, c2_Wr, d_out);
}